// Round 1
// baseline (295.063 us; speedup 1.0000x reference)
//
#include <hip/hip_runtime.h>
#include <math.h>

#define POUT 7
#define NCH 256

// One workgroup (256 threads) per box. Threads 0..195 each own one of the
// 49 bins x 4 subsamples. Per-thread: compute bilinear corners+weights once,
// then loop channels: 4 loads + quad shuffle-reduce + 1 store (quad leader).
__global__ __launch_bounds__(256, 4) void roi_align_kernel(
    const float* __restrict__ f0, const float* __restrict__ f1,
    const float* __restrict__ f2, const float* __restrict__ f3,
    const float* __restrict__ props, float* __restrict__ out, int boxes_per_img)
{
    const int n = blockIdx.x;          // box index
    const int t = threadIdx.x;
    if (t >= 196) return;              // 49 bins * 4 samples
    const int bin = t >> 2;            // 0..48
    const int q   = t & 3;             // sample within bin
    const int ph = bin / POUT, pw = bin % POUT;
    const int iy = q >> 1,     ix = q & 1;

    const int b = n / boxes_per_img;   // image index

    const float4 box = ((const float4*)props)[n];
    const float x0b = box.x, y0b = box.y, x1b = box.z, y1b = box.w;

    // FPN level assignment (matches reference fp32 math)
    const float area = (x1b - x0b) * (y1b - y0b);
    const float side = sqrtf(area);
    float lvl = floorf(4.0f + log2f(side / 224.0f + 1e-6f));
    lvl = fminf(fmaxf(lvl, 2.0f), 5.0f) - 2.0f;
    const int l = (int)lvl;            // 0..3

    const float* feat;
    int sz;
    if      (l == 0) { feat = f0; sz = 200; }
    else if (l == 1) { feat = f1; sz = 100; }
    else if (l == 2) { feat = f2; sz = 50;  }
    else             { feat = f3; sz = 25;  }
    const float scale = 0.25f / (float)(1 << l);

    const float x0 = x0b * scale, y0 = y0b * scale;
    const float x1 = x1b * scale, y1 = y1b * scale;
    const float roi_w = fmaxf(x1 - x0, 1.0f);
    const float roi_h = fmaxf(y1 - y0, 1.0f);
    const float bin_w = roi_w / (float)POUT;
    const float bin_h = roi_h / (float)POUT;

    // sample coordinate (matches reference: off = p + (i+0.5)/SR)
    const float ys = y0 + ((float)ph + ((float)iy + 0.5f) * 0.5f) * bin_h;
    const float xs = x0 + ((float)pw + ((float)ix + 0.5f) * 0.5f) * bin_w;

    // prep y
    const bool  vy  = (ys >= -1.0f) && (ys <= (float)sz);
    const float cy  = fmaxf(ys, 0.0f);
    const int   yl0 = (int)floorf(cy);
    const bool  ey  = yl0 >= sz - 1;
    const int   yl  = ey ? sz - 1 : yl0;
    const int   yh  = ey ? sz - 1 : yl0 + 1;
    const float ly  = ey ? 0.0f : cy - (float)yl0;
    // prep x
    const bool  vx  = (xs >= -1.0f) && (xs <= (float)sz);
    const float cx  = fmaxf(xs, 0.0f);
    const int   xl0 = (int)floorf(cx);
    const bool  ex  = xl0 >= sz - 1;
    const int   xl  = ex ? sz - 1 : xl0;
    const int   xh  = ex ? sz - 1 : xl0 + 1;
    const float lx  = ex ? 0.0f : cx - (float)xl0;

    const float hy = 1.0f - ly, hx = 1.0f - lx;
    const float m  = (vy && vx) ? 1.0f : 0.0f;
    const float w00 = hy * hx * m;
    const float w01 = hy * lx * m;
    const float w10 = ly * hx * m;
    const float w11 = ly * lx * m;

    const int HW = sz * sz;                      // <= 40000
    const float* base = feat + (size_t)b * NCH * HW;
    int o00 = yl * sz + xl;
    int o01 = yl * sz + xh;
    int o10 = yh * sz + xl;
    int o11 = yh * sz + xh;

    float* op = out + (size_t)n * NCH * (POUT * POUT) + bin;

    #pragma unroll 4
    for (int c = 0; c < NCH; ++c) {
        float v = w00 * base[o00] + w01 * base[o01]
                + w10 * base[o10] + w11 * base[o11];
        // reduce the 4 subsamples of this bin (lanes q=0..3 within a quad)
        v += __shfl_xor(v, 1);
        v += __shfl_xor(v, 2);
        if (q == 0) op[c * (POUT * POUT)] = v * 0.25f;
        o00 += HW; o01 += HW; o10 += HW; o11 += HW;
    }
}

extern "C" void kernel_launch(void* const* d_in, const int* in_sizes, int n_in,
                              void* d_out, int out_size, void* d_ws, size_t ws_size,
                              hipStream_t stream) {
    const float* f0 = (const float*)d_in[0];
    const float* f1 = (const float*)d_in[1];
    const float* f2 = (const float*)d_in[2];
    const float* f3 = (const float*)d_in[3];
    const float* props = (const float*)d_in[4];
    float* out = (float*)d_out;

    const int N = in_sizes[4] / 4;                       // total boxes (1024)
    const int B = in_sizes[0] / (NCH * 200 * 200);       // images (2)
    const int boxes_per_img = N / B;                     // 512

    roi_align_kernel<<<N, 256, 0, stream>>>(f0, f1, f2, f3, props, out, boxes_per_img);
}